// Round 6
// baseline (381.416 us; speedup 1.0000x reference)
//
#include <hip/hip_runtime.h>
#include <math.h>

#define BATCH 4
#define CH    512
#define ICH   256
#define NPIX  4096   // 64*64

typedef short short8 __attribute__((ext_vector_type(8)));
typedef float floatx4 __attribute__((ext_vector_type(4)));

#define BK   64
#define TS   136   // epilogue LDS tile stride (272B rows; <=2-way bank alias)

static __device__ __forceinline__ unsigned short f2bf(float x) {
    union { float f; unsigned u; } v; v.f = x;
    unsigned r = (v.u + 0x7FFF + ((v.u >> 16) & 1)) >> 16;   // RNE
    return (unsigned short)r;
}
static __device__ __forceinline__ float bf2f(unsigned short u) {
    union { unsigned u; float f; } v; v.u = ((unsigned)u) << 16; return v.f;
}
// pack two fp32 (even lane's, odd lane's) to bf16 pair, round-half-up
static __device__ __forceinline__ unsigned pack_bf(unsigned ue, unsigned uo) {
    return ((ue + 0x8000u) >> 16) | ((uo + 0x8000u) & 0xFFFF0000u);
}

// async global->LDS, 16B per lane. dst must be wave-uniform; HW adds lane*16.
static __device__ __forceinline__ void gld16(const unsigned short* g, unsigned short* l) {
    __builtin_amdgcn_global_load_lds(
        (const __attribute__((address_space(1))) unsigned int*)g,
        (__attribute__((address_space(3))) unsigned int*)l,
        16, 0, 0);
}

// Swizzled unpadded tile: row r (64 shorts) at LDS r*64; chunk c at pos c^(r&7).
// 256-thread version (4 waves, 32 rows per issue) — used by conv kernel.
#define STAGE_TILE(L, M, row0, RS, k0)                                        \
    {                                                                         \
        int r_  = (it*32) + wid*8 + (lane >> 3);                              \
        int c_  = (lane & 7) ^ ((lane >> 3) & 7);                             \
        gld16(&(M)[(size_t)((row0) + r_)*(RS) + (k0) + c_*8],                 \
              &(L)[(it*32 + wid*8)*64]);                                      \
    }

// 512-thread version (8 waves, 64 rows per issue) — used by dots/pv kernels.
#define STG64(L, M, row0, RS, k0, u)                                          \
    {                                                                         \
        int r_  = (u)*64 + wid*8 + (lane >> 3);                               \
        int c_  = (lane & 7) ^ ((lane >> 3) & 7);                             \
        gld16(&(M)[(size_t)((row0) + r_)*(RS) + (k0) + c_*8],                 \
              &(L)[((u)*64 + wid*8)*64]);                                     \
    }

#define FRAG(L, row, ks) \
    (*(const short8*)&(L)[(row)*64 + (((((ks)<<2) + quad) ^ (lo & 7)) << 3)])

// ---------------------------------------------------------------------------
// prep_w: qw/kw/vw fp32 -> Wb[1024][512] bf16 (rows: 0-255 Q, 256-511 K, 512-1023 V)
// ---------------------------------------------------------------------------
__global__ __launch_bounds__(256)
void prep_w(const float* __restrict__ qw, const float* __restrict__ kw,
            const float* __restrict__ vw, unsigned short* __restrict__ Wb)
{
    int i = (blockIdx.x*256 + threadIdx.x) * 4;
    const float* src;
    int off;
    if (i < 256*512)            { src = qw; off = i; }
    else if (i < 512*512)       { src = kw; off = i - 256*512; }
    else                        { src = vw; off = i - 512*512; }
    float4 f = *(const float4*)&src[off];
    unsigned short pk[4] = { f2bf(f.x), f2bf(f.y), f2bf(f.z), f2bf(f.w) };
    *(uint2*)&Wb[i] = *(uint2*)pk;
}

// ---------------------------------------------------------------------------
// prep_ft: feat [b][c][n] fp32 -> Ft [b][n][c] bf16. grid (64, 8, B).
// ---------------------------------------------------------------------------
__global__ __launch_bounds__(256)
void prep_ft(const float* __restrict__ feat, unsigned short* __restrict__ Ft)
{
    __shared__ unsigned short S[64][65];
    const int t = threadIdx.x;
    const int n0 = blockIdx.x * 64, c0 = blockIdx.y * 64, b = blockIdx.z;

    #pragma unroll
    for (int rep = 0; rep < 4; rep++) {
        int cl = rep*16 + (t >> 4), col4 = (t & 15) * 4;
        float4 f = *(const float4*)&feat[((size_t)b*CH + c0 + cl)*NPIX + n0 + col4];
        S[cl][col4 + 0] = f2bf(f.x);
        S[cl][col4 + 1] = f2bf(f.y);
        S[cl][col4 + 2] = f2bf(f.z);
        S[cl][col4 + 3] = f2bf(f.w);
    }
    __syncthreads();
    #pragma unroll
    for (int rep = 0; rep < 4; rep++) {
        int nn = rep*16 + (t >> 4), cq = t & 15;
        unsigned short h4[4];
        #pragma unroll
        for (int j = 0; j < 4; j++) h4[j] = S[cq*4 + j][nn];
        *(uint2*)&Ft[((size_t)b*NPIX + n0 + nn)*CH + c0 + cq*4] = *(uint2*)h4;
    }
}

// ---------------------------------------------------------------------------
// conv_mfma: fused QKV conv as bf16 MFMA GEMM, K=512 (serial form:
// 34.8KB LDS, ~4 blocks/CU — TLP hides staging latency; dbuf regressed).
// grid (32, 8, B); block 256.
// ---------------------------------------------------------------------------
__global__ __launch_bounds__(256)
void conv_mfma(const unsigned short* __restrict__ Ft,
               const unsigned short* __restrict__ Wb,
               const float* __restrict__ qb, const float* __restrict__ kb,
               const float* __restrict__ vb,
               const float* __restrict__ cw, const float* __restrict__ cb,
               unsigned short* __restrict__ Qt, unsigned short* __restrict__ Kt,
               unsigned short* __restrict__ Vt)
{
    __shared__ unsigned short SH[128*TS];   // 34816B; staging uses first 32KB
    unsigned short* L0 = SH;                // Ft tile (rows n), 128*64
    unsigned short* L2 = SH + 128*64;       // W tile (rows o), 128*64

    const int tid = threadIdx.x;
    const int wid = tid >> 6, lane = tid & 63, quad = lane >> 4, lo = lane & 15;
    const int n0 = blockIdx.x * 128;
    const int yb = blockIdx.y;
    const int bz = blockIdx.z;
    const int o_base = yb * 128;
    const int waveA = (wid >> 1) * 64, waveB = (wid & 1) * 64;
    const int is_v = (yb >= 4);
    const size_t fb = (size_t)bz*NPIX;

    floatx4 acc[4][4] = {};

    for (int k0 = 0; k0 < CH; k0 += BK) {
        #pragma unroll
        for (int it = 0; it < 4; it++) {
            STAGE_TILE(L0, Ft, fb + n0, CH, k0);
            STAGE_TILE(L2, Wb, o_base,  CH, k0);
        }
        __syncthreads();
        if (!is_v) {
            #pragma unroll
            for (int ks = 0; ks < 2; ks++) {
                short8 af[4], bw[4];
                #pragma unroll
                for (int i = 0; i < 4; i++) af[i] = FRAG(L0, waveA + i*16 + lo, ks);
                #pragma unroll
                for (int j = 0; j < 4; j++) bw[j] = FRAG(L2, waveB + j*16 + lo, ks);
                #pragma unroll
                for (int i = 0; i < 4; i++)
                    #pragma unroll
                    for (int j = 0; j < 4; j++)
                        acc[i][j] = __builtin_amdgcn_mfma_f32_16x16x32_bf16(af[i], bw[j], acc[i][j], 0, 0, 0);
            }
        } else {
            #pragma unroll
            for (int ks = 0; ks < 2; ks++) {
                short8 aw[4], bf[4];
                #pragma unroll
                for (int i = 0; i < 4; i++) aw[i] = FRAG(L2, waveA + i*16 + lo, ks);
                #pragma unroll
                for (int j = 0; j < 4; j++) bf[j] = FRAG(L0, waveB + j*16 + lo, ks);
                #pragma unroll
                for (int i = 0; i < 4; i++)
                    #pragma unroll
                    for (int j = 0; j < 4; j++)
                        acc[i][j] = __builtin_amdgcn_mfma_f32_16x16x32_bf16(aw[i], bf[j], acc[i][j], 0, 0, 0);
            }
        }
        __syncthreads();
    }

    // epilogue phase 1: values -> LDS tile [row 128][col 128], pair-packed dwords.
    const float step = 2.0f / 63.0f;
    if (!is_v) {
        const float* bp = (yb < 2) ? qb : kb;
        const int icg0 = (yb & 1) * 128;
        #pragma unroll
        for (int ib = 0; ib < 4; ib++) {
            int colL = waveB + ib*16 + lo;
            int ic = icg0 + colL;
            float bias = bp[ic];
            float cw0 = cw[ic*2+0], cw1 = cw[ic*2+1], cbv = cb[ic];
            #pragma unroll
            for (int ia = 0; ia < 4; ia++) {
                int rowL = waveA + ia*16 + quad*4;
                #pragma unroll
                for (int r = 0; r < 4; r++) {
                    int n = n0 + rowL + r;
                    float cx = -1.f + (n & 63)*step;
                    float cy = -1.f + (n >> 6)*step;
                    float v = fmaxf(acc[ia][ib][r] + bias, 0.f)
                            + fmaxf(cw0*cx + cw1*cy + cbv, 0.f);
                    unsigned u = __float_as_uint(v);
                    unsigned p = __shfl_xor(u, 1, 64);
                    if ((lo & 1) == 0)
                        *(unsigned*)&SH[(rowL + r)*TS + colL] = pack_bf(u, p);
                }
            }
        }
    } else {
        const int c_blk0 = (yb - 4) * 128;
        #pragma unroll
        for (int ia = 0; ia < 4; ia++) {
            int rowL = waveA + ia*16 + quad*4;
            #pragma unroll
            for (int r = 0; r < 4; r++) {
                float bias = vb[c_blk0 + rowL + r];
                #pragma unroll
                for (int ib = 0; ib < 4; ib++) {
                    int colL = waveB + ib*16 + lo;
                    float v = fmaxf(acc[ia][ib][r] + bias, 0.f);
                    unsigned u = __float_as_uint(v);
                    unsigned p = __shfl_xor(u, 1, 64);
                    if ((lo & 1) == 0)
                        *(unsigned*)&SH[(rowL + r)*TS + colL] = pack_bf(u, p);
                }
            }
        }
    }
    __syncthreads();

    // epilogue phase 2: coalesced copy to global (256B per row segment)
    unsigned short* dstp;
    int row0, rs, col0;
    if (!is_v) { dstp = ((yb < 2) ? Qt : Kt) + (size_t)bz*NPIX*ICH;
                 row0 = n0; rs = ICH; col0 = (yb & 1) * 128; }
    else       { dstp = Vt + (size_t)bz*CH*NPIX;
                 row0 = (yb - 4) * 128; rs = NPIX; col0 = n0; }
    #pragma unroll
    for (int it = 0; it < 8; it++) {
        int f = it*256 + tid;
        int row = f >> 4, col = (f & 15) * 8;
        uint4 v = *(const uint4*)&SH[row*TS + col];
        *(uint4*)&dstp[(size_t)(row0 + row)*rs + col0 + col] = v;
    }
}

// ---------------------------------------------------------------------------
// asq[n] = |q_n|^2, bsq[n] = |k_n|^2 from bf16 Qt/Kt [n][ic]. grid (16, B).
// ---------------------------------------------------------------------------
__global__ __launch_bounds__(256)
void sqb_kernel(const unsigned short* __restrict__ Qt,
                const unsigned short* __restrict__ Kt,
                float* __restrict__ asq, float* __restrict__ bsq)
{
    int n = blockIdx.x*256 + threadIdx.x;
    int b = blockIdx.y;
    const unsigned short* q = Qt + ((size_t)b*NPIX + n)*ICH;
    const unsigned short* k = Kt + ((size_t)b*NPIX + n)*ICH;
    float qs = 0.f, ks = 0.f;
    #pragma unroll 4
    for (int i = 0; i < ICH/8; i++) {
        uint4 v = *(const uint4*)&q[i*8];
        const unsigned short* s = (const unsigned short*)&v;
        #pragma unroll
        for (int j = 0; j < 8; j++) { float a = bf2f(s[j]); qs += a*a; }
        uint4 w = *(const uint4*)&k[i*8];
        const unsigned short* t = (const unsigned short*)&w;
        #pragma unroll
        for (int j = 0; j < 8; j++) { float a = bf2f(t[j]); ks += a*a; }
    }
    asq[b*NPIX + n] = qs;
    bsq[b*NPIX + n] = ks;
}

// ---------------------------------------------------------------------------
// St[bz][m][n] = exp(-(asq[n]+bsq[m]-2*k_m.q_n)) bf16 + col sums -> rsum[n].
// High-TLP variant: 128x128 tile, serial K-loop, 512 threads / 8 waves
// (wave-tile 64x32, acc[4][2]). 16 waves/CU.
// grid (32, 32, nb); block 512. LDS 34.8KB.
// ---------------------------------------------------------------------------
__global__ __launch_bounds__(512)
void dots_mfma(const unsigned short* __restrict__ Kt_,
               const unsigned short* __restrict__ Qt_,
               const float* __restrict__ asq_, const float* __restrict__ bsq_,
               unsigned short* __restrict__ St_, float* __restrict__ rsum_,
               int b0)
{
    __shared__ unsigned short SH[128*TS];   // 34816B; staging uses first 32KB
    unsigned short* Al = SH;                // Kt tile (rows m), 128*64
    unsigned short* Bl = SH + 8192;         // Qt tile (rows n), 128*64

    const int tid = threadIdx.x;
    const int wid = tid >> 6, lane = tid & 63, quad = lane >> 4, lo = lane & 15;
    const int wm = wid >> 2;          // 0..1 : m-dim (64 rows each)
    const int wn = wid & 3;           // 0..3 : n-dim (32 cols each)
    const int m0 = blockIdx.x * 128, n0 = blockIdx.y * 128;
    const int bz = blockIdx.z, gb = b0 + bz;

    const unsigned short* Kt = Kt_ + (size_t)gb*NPIX*ICH;
    const unsigned short* Qt = Qt_ + (size_t)gb*NPIX*ICH;
    const float* asq = asq_ + (size_t)gb*NPIX;
    const float* bsq = bsq_ + (size_t)gb*NPIX;
    unsigned short* St = St_ + (size_t)bz*NPIX*NPIX;
    float* rsum = rsum_ + (size_t)gb*NPIX;

    floatx4 acc[4][2] = {};   // [i: m frag][j: n frag]

    for (int k0 = 0; k0 < ICH; k0 += BK) {
        STG64(Al, Kt, m0, ICH, k0, 0);
        STG64(Al, Kt, m0, ICH, k0, 1);
        STG64(Bl, Qt, n0, ICH, k0, 0);
        STG64(Bl, Qt, n0, ICH, k0, 1);
        __syncthreads();
        #pragma unroll
        for (int ks = 0; ks < 2; ks++) {
            short8 a[4], bfr[2];
            #pragma unroll
            for (int i = 0; i < 4; i++) a[i]  = FRAG(Al, wm*64 + i*16 + lo, ks);
            #pragma unroll
            for (int j = 0; j < 2; j++) bfr[j] = FRAG(Bl, wn*32 + j*16 + lo, ks);
            #pragma unroll
            for (int i = 0; i < 4; i++)
                #pragma unroll
                for (int j = 0; j < 2; j++)
                    acc[i][j] = __builtin_amdgcn_mfma_f32_16x16x32_bf16(
                        a[i], bfr[j], acc[i][j], 0, 0, 0);
        }
        __syncthreads();
    }

    // epilogue phase 1: exp(-D) -> LDS tile (pair-pack), colsums
    #pragma unroll
    for (int j = 0; j < 2; j++) {
        int nl = wn*32 + j*16 + lo;
        float aq = asq[n0 + nl];
        float colsum = 0.f;
        #pragma unroll
        for (int i = 0; i < 4; i++) {
            int mb = wm*64 + i*16 + quad*4;
            #pragma unroll
            for (int r = 0; r < 4; r++) {
                float d = aq + bsq[m0 + mb + r] - 2.f*acc[i][j][r];
                float sv = __expf(-d);
                colsum += sv;
                unsigned u = __float_as_uint(sv);
                unsigned p = __shfl_xor(u, 1, 64);
                if ((lo & 1) == 0)
                    *(unsigned*)&SH[(mb + r)*TS + nl] = pack_bf(u, p);
            }
        }
        colsum += __shfl_xor(colsum, 16, 64);
        colsum += __shfl_xor(colsum, 32, 64);
        if (quad == 0) atomicAdd(&rsum[n0 + nl], colsum);
    }
    __syncthreads();

    // epilogue phase 2: coalesced store, 256B contiguous per row
    #pragma unroll
    for (int it = 0; it < 4; it++) {
        int f = it*512 + tid;
        int row = f >> 4, col = (f & 15) * 8;
        uint4 v = *(const uint4*)&SH[row*TS + col];
        *(uint4*)&St[(size_t)(m0 + row)*NPIX + n0 + col] = v;
    }
}

// ---------------------------------------------------------------------------
// Vp[c][n] = bf16( Vt[c][n] / (rsum[n] + 1e-14) ). grid (1024, nb).
// ---------------------------------------------------------------------------
__global__ __launch_bounds__(256)
void vscale_kernel(const unsigned short* __restrict__ Vt,
                   const float* __restrict__ rsum,
                   unsigned short* __restrict__ Vp, int b0)
{
    int gb = b0 + blockIdx.y;
    size_t base = (size_t)gb*CH*NPIX + ((size_t)blockIdx.x*256 + threadIdx.x) * 8;
    int n = (int)(base & (NPIX - 1));
    const float* rs = rsum + (size_t)gb*NPIX;
    uint4 v = *(const uint4*)&Vt[base];
    const unsigned short* s = (const unsigned short*)&v;
    unsigned short pk[8];
    #pragma unroll
    for (int i = 0; i < 8; i++)
        pk[i] = f2bf(bf2f(s[i]) / (rs[n + i] + 1e-14f));
    *(uint4*)&Vp[base] = *(uint4*)pk;
}

// ---------------------------------------------------------------------------
// out[c][m] = sum_n V'[c][n] * St[m][n] + feat[c][m].
// Port-split deep pipeline: A (Vp) loaded per-lane from GLOBAL into registers
// (L1/L2 path), B (St) staged in LDS via counted-vmcnt 3-buffer schedule.
// LDS reads per K-tile halve (131KB->64KB) -> LDS port no longer the bound.
// BM=128(c) x BN=256(m) x BK=64, 512 thr (8 waves 2x4, 64x64/wave).
// Steady state: each step issues 12 vmem/wave (4 B-stage + 8 A-loads);
// end-of-step vmcnt(12) guarantees B_{s+1} landed, keeps s+2 in flight.
// grid (16, 4, nb); block 512. LDS 96KB, 1 block/CU.
// ---------------------------------------------------------------------------
#define PVB  16384           // shorts per B buffer (256 rows x 64)
#define PVNT (NPIX/BK)       // 64 K-tiles

#define PV_STEP(s, AC, AN)                                                    \
    {                                                                         \
        unsigned short* Bc = SH3 + pc*PVB;                                    \
        int pn_ = pc + 2; if (pn_ >= 3) pn_ -= 3;                             \
        unsigned short* Bn = SH3 + pn_*PVB;                                   \
        const int k2 = ((s) + 2) * BK;                                        \
        const bool stg = ((s) < PVNT - 2);                                    \
        short8 b01[2][2], b23[2][2];                                          \
        _Pragma("unroll")                                                     \
        for (int ks = 0; ks < 2; ks++)                                        \
            _Pragma("unroll")                                                 \
            for (int j = 0; j < 2; j++)                                       \
                b01[ks][j] = FRAG(Bc, wn*64 + j*16 + lo, ks);                 \
        if (stg) {                                                            \
            STG64(Bn, St, m0, NPIX, k2, 0);                                   \
            STG64(Bn, St, m0, NPIX, k2, 1);                                   \
        }                                                                     \
        if ((s) + 1 < PVNT) {                                                 \
            _Pragma("unroll")                                                 \
            for (int ks = 0; ks < 2; ks++)                                    \
                _Pragma("unroll")                                             \
                for (int i = 0; i < 4; i++)                                   \
                    AN[ks][i] = *(const short8*)(ap[i] + ((s)+1)*64 + ks*32); \
        }                                                                     \
        __builtin_amdgcn_s_barrier();                                         \
        __builtin_amdgcn_s_setprio(1);                                        \
        _Pragma("unroll")                                                     \
        for (int ks = 0; ks < 2; ks++)                                        \
            _Pragma("unroll")                                                 \
            for (int i = 0; i < 4; i++)                                       \
                _Pragma("unroll")                                             \
                for (int j = 0; j < 2; j++)                                   \
                    acc[i][j] = __builtin_amdgcn_mfma_f32_16x16x32_bf16(      \
                        AC[ks][i], b01[ks][j], acc[i][j], 0, 0, 0);           \
        __builtin_amdgcn_s_setprio(0);                                        \
        __builtin_amdgcn_s_barrier();                                         \
        _Pragma("unroll")                                                     \
        for (int ks = 0; ks < 2; ks++)                                        \
            _Pragma("unroll")                                                 \
            for (int j = 0; j < 2; j++)                                       \
                b23[ks][j] = FRAG(Bc, wn*64 + (j+2)*16 + lo, ks);             \
        if (stg) {                                                            \
            STG64(Bn, St, m0, NPIX, k2, 2);                                   \
            STG64(Bn, St, m0, NPIX, k2, 3);                                   \
        }                                                                     \
        __builtin_amdgcn_s_barrier();                                         \
        __builtin_amdgcn_s_setprio(1);                                        \
        _Pragma("unroll")                                                     \
        for (int ks = 0; ks < 2; ks++)                                        \
            _Pragma("unroll")                                                 \
            for (int i = 0; i < 4; i++)                                       \
                _Pragma("unroll")                                             \
                for (int j = 0; j < 2; j++)                                   \
                    acc[i][j+2] = __builtin_amdgcn_mfma_f32_16x16x32_bf16(    \
                        AC[ks][i], b23[ks][j], acc[i][j+2], 0, 0, 0);         \
        __builtin_amdgcn_s_setprio(0);                                        \
        if (stg)                     asm volatile("s_waitcnt vmcnt(12)" ::: "memory"); \
        else if ((s) == PVNT - 2)    asm volatile("s_waitcnt vmcnt(8)"  ::: "memory"); \
        __builtin_amdgcn_s_barrier();                                         \
        pc = pc + 1; if (pc >= 3) pc = 0;                                     \
    }

__global__ __launch_bounds__(512)
void pv_mfma(const unsigned short* __restrict__ Vp_,
             const unsigned short* __restrict__ St_,
             const float* __restrict__ feat_, float* __restrict__ out_,
             int b0)
{
    __shared__ unsigned short SH3[3*PVB];   // 98304 B (B operand only)
    const int tid = threadIdx.x;
    const int wid = tid >> 6, lane = tid & 63, quad = lane >> 4, lo = lane & 15;
    const int wm = wid >> 2;          // 0..1 : c-dim (A operand)
    const int wn = wid & 3;           // 0..3 : m-dim (B operand)
    const int m0 = blockIdx.x * 256, c0 = blockIdx.y * 128;
    const int bz = blockIdx.z, gb = b0 + bz;

    const unsigned short* Vp = Vp_ + (size_t)gb*CH*NPIX;
    const unsigned short* St = St_ + (size_t)bz*NPIX*NPIX;
    const float* feat = feat_ + (size_t)gb*CH*NPIX;
    float* out = out_ + (size_t)gb*CH*NPIX;

    floatx4 acc[4][4] = {};   // [i: c frag][j: m frag]

    // per-lane A row pointers: row = c0 + wm*64 + i*16 + lo, k-offset quad*8
    const unsigned short* ap[4];
    #pragma unroll
    for (int i = 0; i < 4; i++)
        ap[i] = Vp + (size_t)(c0 + wm*64 + i*16 + lo)*NPIX + quad*8;

    short8 aA[2][4], aB[2][4];

    // ---- prologue: stage B-tile 0 -> buf0, B-tile 1 -> buf1; A-tile 0 -> regs
    STG64(SH3,       St, m0, NPIX, 0,  0); STG64(SH3,       St, m0, NPIX, 0,  1);
    STG64(SH3,       St, m0, NPIX, 0,  2); STG64(SH3,       St, m0, NPIX, 0,  3);
    STG64(SH3 + PVB, St, m0, NPIX, BK, 0); STG64(SH3 + PVB, St, m0, NPIX, BK, 1);
    STG64(SH3 + PVB, St, m0, NPIX, BK, 2); STG64(SH3 + PVB, St, m0, NPIX, BK, 3);
    #pragma unroll
    for (int ks = 0; ks < 2; ks++)
        #pragma unroll
        for (int i = 0; i < 4; i++)
            aA[ks][i] = *(const short8*)(ap[i] + ks*32);
    asm volatile("s_waitcnt vmcnt(0)" ::: "memory");   // one-time full drain
    __builtin_amdgcn_s_barrier();

    int pc = 0;
    for (int t = 0; t < PVNT/2; ++t) {
        PV_STEP(2*t,     aA, aB);
        PV_STEP(2*t + 1, aB, aA);
    }

    // epilogue: direct store out = acc + feat (16-lane / 64B contiguous runs)
    #pragma unroll
    for (int i = 0; i < 4; i++) {
        int cr = c0 + wm*64 + i*16 + quad*4;
        #pragma unroll
        for (int r = 0; r < 4; r++) {
            size_t rowbase = (size_t)(cr + r)*NPIX;
            #pragma unroll
            for (int j = 0; j < 4; j++) {
                int m = m0 + wn*64 + j*16 + lo;
                out[rowbase + m] = acc[i][j][r] + feat[rowbase + m];
            }
        }
    }
}

// ---------------------------------------------------------------------------
extern "C" void kernel_launch(void* const* d_in, const int* in_sizes, int n_in,
                              void* d_out, int out_size, void* d_ws, size_t ws_size,
                              hipStream_t stream)
{
    const float* feat = (const float*)d_in[0];
    const float* qw   = (const float*)d_in[1];
    const float* qb   = (const float*)d_in[2];
    const float* kw   = (const float*)d_in[3];
    const float* kb   = (const float*)d_in[4];
    const float* vw   = (const float*)d_in[5];
    const float* vb   = (const float*)d_in[6];
    const float* cw   = (const float*)d_in[7];
    const float* cb   = (const float*)d_in[8];
    float* out = (float*)d_out;
    char* ws = (char*)d_ws;
    char* ws0 = ws;

    unsigned short* Ft  = (unsigned short*)ws;  ws += (size_t)BATCH*NPIX*CH*2;   // 16.78 MB
    unsigned short* Wb  = (unsigned short*)ws;  ws += (size_t)1024*CH*2;         // 1.05 MB
    unsigned short* Qt  = (unsigned short*)ws;  ws += (size_t)BATCH*NPIX*ICH*2;  // 8.39 MB
    unsigned short* Kt  = (unsigned short*)ws;  ws += (size_t)BATCH*NPIX*ICH*2;  // 8.39 MB
    unsigned short* Vt  = (unsigned short*)ws;  ws += (size_t)BATCH*CH*NPIX*2;   // 16.78 MB
    unsigned short* Vp  = (unsigned short*)ws;  ws += (size_t)BATCH*CH*NPIX*2;   // 16.78 MB
    float*         asq  = (float*)ws;           ws += (size_t)BATCH*NPIX*4;
    float*         bsq  = (float*)ws;           ws += (size_t)BATCH*NPIX*4;
    float*         rsum = (float*)ws;           ws += (size_t)BATCH*NPIX*4;
    unsigned short* St  = (unsigned short*)ws;  // nb * 33.55 MB

    const size_t st1 = (size_t)NPIX*NPIX*2;
    const size_t fixed = (size_t)(ws - ws0);
    const int nb = (ws_size >= fixed + (size_t)BATCH*st1) ? BATCH : 1;

    hipMemsetAsync(rsum, 0, (size_t)BATCH*NPIX*sizeof(float), stream);

    prep_w<<<dim3(512), 256, 0, stream>>>(qw, kw, vw, Wb);
    prep_ft<<<dim3(NPIX/64, CH/64, BATCH), 256, 0, stream>>>(feat, Ft);

    conv_mfma<<<dim3(NPIX/128, 8, BATCH), 256, 0, stream>>>(
        Ft, Wb, qb, kb, vb, cw, cb, Qt, Kt, Vt);

    sqb_kernel<<<dim3(NPIX/256, BATCH), 256, 0, stream>>>(Qt, Kt, asq, bsq);

    for (int b0 = 0; b0 < BATCH; b0 += nb) {
        dots_mfma<<<dim3(NPIX/128, NPIX/128, nb), 512, 0, stream>>>(
            Kt, Qt, asq, bsq, St, rsum, b0);
        vscale_kernel<<<dim3(CH*NPIX/(256*8), nb), 256, 0, stream>>>(
            Vt, rsum, Vp, b0);
        pv_mfma<<<dim3(NPIX/256, CH/128, nb), 512, 0, stream>>>(
            Vp, St, feat, out, b0);
    }
}

// Round 7
// 294.533 us; speedup vs baseline: 1.2950x; 1.2950x over previous
//
#include <hip/hip_runtime.h>
#include <math.h>

#define BATCH 4
#define CH    512
#define ICH   256
#define NPIX  4096   // 64*64

typedef short short8 __attribute__((ext_vector_type(8)));
typedef float floatx4 __attribute__((ext_vector_type(4)));

#define BK   64
#define TS   136   // epilogue LDS tile stride (272B rows; <=2-way bank alias)

static __device__ __forceinline__ unsigned short f2bf(float x) {
    union { float f; unsigned u; } v; v.f = x;
    unsigned r = (v.u + 0x7FFF + ((v.u >> 16) & 1)) >> 16;   // RNE
    return (unsigned short)r;
}
static __device__ __forceinline__ float bf2f(unsigned short u) {
    union { unsigned u; float f; } v; v.u = ((unsigned)u) << 16; return v.f;
}
// pack two fp32 (even lane's, odd lane's) to bf16 pair, round-half-up
static __device__ __forceinline__ unsigned pack_bf(unsigned ue, unsigned uo) {
    return ((ue + 0x8000u) >> 16) | ((uo + 0x8000u) & 0xFFFF0000u);
}

// async global->LDS, 16B per lane. dst must be wave-uniform; HW adds lane*16.
static __device__ __forceinline__ void gld16(const unsigned short* g, unsigned short* l) {
    __builtin_amdgcn_global_load_lds(
        (const __attribute__((address_space(1))) unsigned int*)g,
        (__attribute__((address_space(3))) unsigned int*)l,
        16, 0, 0);
}

// Swizzled unpadded tile: row r (64 shorts) at LDS r*64; chunk c at pos c^(r&7).
// 256-thread version (4 waves, 32 rows per issue) — used by conv kernel.
#define STAGE_TILE(L, M, row0, RS, k0)                                        \
    {                                                                         \
        int r_  = (it*32) + wid*8 + (lane >> 3);                              \
        int c_  = (lane & 7) ^ ((lane >> 3) & 7);                             \
        gld16(&(M)[(size_t)((row0) + r_)*(RS) + (k0) + c_*8],                 \
              &(L)[(it*32 + wid*8)*64]);                                      \
    }

// 512-thread version (8 waves, 64 rows per issue) — used by dots/pv kernels.
#define STG64(L, M, row0, RS, k0, u)                                          \
    {                                                                         \
        int r_  = (u)*64 + wid*8 + (lane >> 3);                               \
        int c_  = (lane & 7) ^ ((lane >> 3) & 7);                             \
        gld16(&(M)[(size_t)((row0) + r_)*(RS) + (k0) + c_*8],                 \
              &(L)[((u)*64 + wid*8)*64]);                                     \
    }

#define FRAG(L, row, ks) \
    (*(const short8*)&(L)[(row)*64 + (((((ks)<<2) + quad) ^ (lo & 7)) << 3)])

// ---------------------------------------------------------------------------
// prep_w: qw/kw/vw fp32 -> Wb[1024][512] bf16 (rows: 0-255 Q, 256-511 K, 512-1023 V)
// ---------------------------------------------------------------------------
__global__ __launch_bounds__(256)
void prep_w(const float* __restrict__ qw, const float* __restrict__ kw,
            const float* __restrict__ vw, unsigned short* __restrict__ Wb)
{
    int i = (blockIdx.x*256 + threadIdx.x) * 4;
    const float* src;
    int off;
    if (i < 256*512)            { src = qw; off = i; }
    else if (i < 512*512)       { src = kw; off = i - 256*512; }
    else                        { src = vw; off = i - 512*512; }
    float4 f = *(const float4*)&src[off];
    unsigned short pk[4] = { f2bf(f.x), f2bf(f.y), f2bf(f.z), f2bf(f.w) };
    *(uint2*)&Wb[i] = *(uint2*)pk;
}

// ---------------------------------------------------------------------------
// prep_ft: feat [b][c][n] fp32 -> Ft [b][n][c] bf16. grid (64, 8, B).
// ---------------------------------------------------------------------------
__global__ __launch_bounds__(256)
void prep_ft(const float* __restrict__ feat, unsigned short* __restrict__ Ft)
{
    __shared__ unsigned short S[64][65];
    const int t = threadIdx.x;
    const int n0 = blockIdx.x * 64, c0 = blockIdx.y * 64, b = blockIdx.z;

    #pragma unroll
    for (int rep = 0; rep < 4; rep++) {
        int cl = rep*16 + (t >> 4), col4 = (t & 15) * 4;
        float4 f = *(const float4*)&feat[((size_t)b*CH + c0 + cl)*NPIX + n0 + col4];
        S[cl][col4 + 0] = f2bf(f.x);
        S[cl][col4 + 1] = f2bf(f.y);
        S[cl][col4 + 2] = f2bf(f.z);
        S[cl][col4 + 3] = f2bf(f.w);
    }
    __syncthreads();
    #pragma unroll
    for (int rep = 0; rep < 4; rep++) {
        int nn = rep*16 + (t >> 4), cq = t & 15;
        unsigned short h4[4];
        #pragma unroll
        for (int j = 0; j < 4; j++) h4[j] = S[cq*4 + j][nn];
        *(uint2*)&Ft[((size_t)b*NPIX + n0 + nn)*CH + c0 + cq*4] = *(uint2*)h4;
    }
}

// ---------------------------------------------------------------------------
// conv_mfma: fused QKV conv as bf16 MFMA GEMM, K=512 (serial form:
// 34.8KB LDS, ~4 blocks/CU — TLP hides staging latency; dbuf regressed).
// grid (32, 8, B); block 256.
// ---------------------------------------------------------------------------
__global__ __launch_bounds__(256)
void conv_mfma(const unsigned short* __restrict__ Ft,
               const unsigned short* __restrict__ Wb,
               const float* __restrict__ qb, const float* __restrict__ kb,
               const float* __restrict__ vb,
               const float* __restrict__ cw, const float* __restrict__ cb,
               unsigned short* __restrict__ Qt, unsigned short* __restrict__ Kt,
               unsigned short* __restrict__ Vt)
{
    __shared__ unsigned short SH[128*TS];   // 34816B; staging uses first 32KB
    unsigned short* L0 = SH;                // Ft tile (rows n), 128*64
    unsigned short* L2 = SH + 128*64;       // W tile (rows o), 128*64

    const int tid = threadIdx.x;
    const int wid = tid >> 6, lane = tid & 63, quad = lane >> 4, lo = lane & 15;
    const int n0 = blockIdx.x * 128;
    const int yb = blockIdx.y;
    const int bz = blockIdx.z;
    const int o_base = yb * 128;
    const int waveA = (wid >> 1) * 64, waveB = (wid & 1) * 64;
    const int is_v = (yb >= 4);
    const size_t fb = (size_t)bz*NPIX;

    floatx4 acc[4][4] = {};

    for (int k0 = 0; k0 < CH; k0 += BK) {
        #pragma unroll
        for (int it = 0; it < 4; it++) {
            STAGE_TILE(L0, Ft, fb + n0, CH, k0);
            STAGE_TILE(L2, Wb, o_base,  CH, k0);
        }
        __syncthreads();
        if (!is_v) {
            #pragma unroll
            for (int ks = 0; ks < 2; ks++) {
                short8 af[4], bw[4];
                #pragma unroll
                for (int i = 0; i < 4; i++) af[i] = FRAG(L0, waveA + i*16 + lo, ks);
                #pragma unroll
                for (int j = 0; j < 4; j++) bw[j] = FRAG(L2, waveB + j*16 + lo, ks);
                #pragma unroll
                for (int i = 0; i < 4; i++)
                    #pragma unroll
                    for (int j = 0; j < 4; j++)
                        acc[i][j] = __builtin_amdgcn_mfma_f32_16x16x32_bf16(af[i], bw[j], acc[i][j], 0, 0, 0);
            }
        } else {
            #pragma unroll
            for (int ks = 0; ks < 2; ks++) {
                short8 aw[4], bf[4];
                #pragma unroll
                for (int i = 0; i < 4; i++) aw[i] = FRAG(L2, waveA + i*16 + lo, ks);
                #pragma unroll
                for (int j = 0; j < 4; j++) bf[j] = FRAG(L0, waveB + j*16 + lo, ks);
                #pragma unroll
                for (int i = 0; i < 4; i++)
                    #pragma unroll
                    for (int j = 0; j < 4; j++)
                        acc[i][j] = __builtin_amdgcn_mfma_f32_16x16x32_bf16(aw[i], bf[j], acc[i][j], 0, 0, 0);
            }
        }
        __syncthreads();
    }

    // epilogue phase 1: values -> LDS tile [row 128][col 128], pair-packed dwords.
    const float step = 2.0f / 63.0f;
    if (!is_v) {
        const float* bp = (yb < 2) ? qb : kb;
        const int icg0 = (yb & 1) * 128;
        #pragma unroll
        for (int ib = 0; ib < 4; ib++) {
            int colL = waveB + ib*16 + lo;
            int ic = icg0 + colL;
            float bias = bp[ic];
            float cw0 = cw[ic*2+0], cw1 = cw[ic*2+1], cbv = cb[ic];
            #pragma unroll
            for (int ia = 0; ia < 4; ia++) {
                int rowL = waveA + ia*16 + quad*4;
                #pragma unroll
                for (int r = 0; r < 4; r++) {
                    int n = n0 + rowL + r;
                    float cx = -1.f + (n & 63)*step;
                    float cy = -1.f + (n >> 6)*step;
                    float v = fmaxf(acc[ia][ib][r] + bias, 0.f)
                            + fmaxf(cw0*cx + cw1*cy + cbv, 0.f);
                    unsigned u = __float_as_uint(v);
                    unsigned p = __shfl_xor(u, 1, 64);
                    if ((lo & 1) == 0)
                        *(unsigned*)&SH[(rowL + r)*TS + colL] = pack_bf(u, p);
                }
            }
        }
    } else {
        const int c_blk0 = (yb - 4) * 128;
        #pragma unroll
        for (int ia = 0; ia < 4; ia++) {
            int rowL = waveA + ia*16 + quad*4;
            #pragma unroll
            for (int r = 0; r < 4; r++) {
                float bias = vb[c_blk0 + rowL + r];
                #pragma unroll
                for (int ib = 0; ib < 4; ib++) {
                    int colL = waveB + ib*16 + lo;
                    float v = fmaxf(acc[ia][ib][r] + bias, 0.f);
                    unsigned u = __float_as_uint(v);
                    unsigned p = __shfl_xor(u, 1, 64);
                    if ((lo & 1) == 0)
                        *(unsigned*)&SH[(rowL + r)*TS + colL] = pack_bf(u, p);
                }
            }
        }
    }
    __syncthreads();

    // epilogue phase 2: coalesced copy to global (256B per row segment)
    unsigned short* dstp;
    int row0, rs, col0;
    if (!is_v) { dstp = ((yb < 2) ? Qt : Kt) + (size_t)bz*NPIX*ICH;
                 row0 = n0; rs = ICH; col0 = (yb & 1) * 128; }
    else       { dstp = Vt + (size_t)bz*CH*NPIX;
                 row0 = (yb - 4) * 128; rs = NPIX; col0 = n0; }
    #pragma unroll
    for (int it = 0; it < 8; it++) {
        int f = it*256 + tid;
        int row = f >> 4, col = (f & 15) * 8;
        uint4 v = *(const uint4*)&SH[row*TS + col];
        *(uint4*)&dstp[(size_t)(row0 + row)*rs + col0 + col] = v;
    }
}

// ---------------------------------------------------------------------------
// asq[n] = |q_n|^2, bsq[n] = |k_n|^2 from bf16 Qt/Kt [n][ic]. grid (16, B).
// ---------------------------------------------------------------------------
__global__ __launch_bounds__(256)
void sqb_kernel(const unsigned short* __restrict__ Qt,
                const unsigned short* __restrict__ Kt,
                float* __restrict__ asq, float* __restrict__ bsq)
{
    int n = blockIdx.x*256 + threadIdx.x;
    int b = blockIdx.y;
    const unsigned short* q = Qt + ((size_t)b*NPIX + n)*ICH;
    const unsigned short* k = Kt + ((size_t)b*NPIX + n)*ICH;
    float qs = 0.f, ks = 0.f;
    #pragma unroll 4
    for (int i = 0; i < ICH/8; i++) {
        uint4 v = *(const uint4*)&q[i*8];
        const unsigned short* s = (const unsigned short*)&v;
        #pragma unroll
        for (int j = 0; j < 8; j++) { float a = bf2f(s[j]); qs += a*a; }
        uint4 w = *(const uint4*)&k[i*8];
        const unsigned short* t = (const unsigned short*)&w;
        #pragma unroll
        for (int j = 0; j < 8; j++) { float a = bf2f(t[j]); ks += a*a; }
    }
    asq[b*NPIX + n] = qs;
    bsq[b*NPIX + n] = ks;
}

// ---------------------------------------------------------------------------
// St[bz][m][n] = exp(-(asq[n]+bsq[m]-2*k_m.q_n)) bf16 + col sums -> rsum[n].
// High-TLP variant: 128x128 tile, serial K-loop, 512 threads / 8 waves
// (wave-tile 64x32, acc[4][2]). 16 waves/CU.
// grid (32, 32, nb); block 512. LDS 34.8KB.
// ---------------------------------------------------------------------------
__global__ __launch_bounds__(512)
void dots_mfma(const unsigned short* __restrict__ Kt_,
               const unsigned short* __restrict__ Qt_,
               const float* __restrict__ asq_, const float* __restrict__ bsq_,
               unsigned short* __restrict__ St_, float* __restrict__ rsum_,
               int b0)
{
    __shared__ unsigned short SH[128*TS];   // 34816B; staging uses first 32KB
    unsigned short* Al = SH;                // Kt tile (rows m), 128*64
    unsigned short* Bl = SH + 8192;         // Qt tile (rows n), 128*64

    const int tid = threadIdx.x;
    const int wid = tid >> 6, lane = tid & 63, quad = lane >> 4, lo = lane & 15;
    const int wm = wid >> 2;          // 0..1 : m-dim (64 rows each)
    const int wn = wid & 3;           // 0..3 : n-dim (32 cols each)
    const int m0 = blockIdx.x * 128, n0 = blockIdx.y * 128;
    const int bz = blockIdx.z, gb = b0 + bz;

    const unsigned short* Kt = Kt_ + (size_t)gb*NPIX*ICH;
    const unsigned short* Qt = Qt_ + (size_t)gb*NPIX*ICH;
    const float* asq = asq_ + (size_t)gb*NPIX;
    const float* bsq = bsq_ + (size_t)gb*NPIX;
    unsigned short* St = St_ + (size_t)bz*NPIX*NPIX;
    float* rsum = rsum_ + (size_t)gb*NPIX;

    floatx4 acc[4][2] = {};   // [i: m frag][j: n frag]

    for (int k0 = 0; k0 < ICH; k0 += BK) {
        STG64(Al, Kt, m0, ICH, k0, 0);
        STG64(Al, Kt, m0, ICH, k0, 1);
        STG64(Bl, Qt, n0, ICH, k0, 0);
        STG64(Bl, Qt, n0, ICH, k0, 1);
        __syncthreads();
        #pragma unroll
        for (int ks = 0; ks < 2; ks++) {
            short8 a[4], bfr[2];
            #pragma unroll
            for (int i = 0; i < 4; i++) a[i]  = FRAG(Al, wm*64 + i*16 + lo, ks);
            #pragma unroll
            for (int j = 0; j < 2; j++) bfr[j] = FRAG(Bl, wn*32 + j*16 + lo, ks);
            #pragma unroll
            for (int i = 0; i < 4; i++)
                #pragma unroll
                for (int j = 0; j < 2; j++)
                    acc[i][j] = __builtin_amdgcn_mfma_f32_16x16x32_bf16(
                        a[i], bfr[j], acc[i][j], 0, 0, 0);
        }
        __syncthreads();
    }

    // epilogue phase 1: exp(-D) -> LDS tile (pair-pack), colsums
    #pragma unroll
    for (int j = 0; j < 2; j++) {
        int nl = wn*32 + j*16 + lo;
        float aq = asq[n0 + nl];
        float colsum = 0.f;
        #pragma unroll
        for (int i = 0; i < 4; i++) {
            int mb = wm*64 + i*16 + quad*4;
            #pragma unroll
            for (int r = 0; r < 4; r++) {
                float d = aq + bsq[m0 + mb + r] - 2.f*acc[i][j][r];
                float sv = __expf(-d);
                colsum += sv;
                unsigned u = __float_as_uint(sv);
                unsigned p = __shfl_xor(u, 1, 64);
                if ((lo & 1) == 0)
                    *(unsigned*)&SH[(mb + r)*TS + nl] = pack_bf(u, p);
            }
        }
        colsum += __shfl_xor(colsum, 16, 64);
        colsum += __shfl_xor(colsum, 32, 64);
        if (quad == 0) atomicAdd(&rsum[n0 + nl], colsum);
    }
    __syncthreads();

    // epilogue phase 2: coalesced store, 256B contiguous per row
    #pragma unroll
    for (int it = 0; it < 4; it++) {
        int f = it*512 + tid;
        int row = f >> 4, col = (f & 15) * 8;
        uint4 v = *(const uint4*)&SH[row*TS + col];
        *(uint4*)&St[(size_t)(m0 + row)*NPIX + n0 + col] = v;
    }
}

// ---------------------------------------------------------------------------
// Vp[c][n] = bf16( Vt[c][n] / (rsum[n] + 1e-14) ). grid (1024, nb).
// ---------------------------------------------------------------------------
__global__ __launch_bounds__(256)
void vscale_kernel(const unsigned short* __restrict__ Vt,
                   const float* __restrict__ rsum,
                   unsigned short* __restrict__ Vp, int b0)
{
    int gb = b0 + blockIdx.y;
    size_t base = (size_t)gb*CH*NPIX + ((size_t)blockIdx.x*256 + threadIdx.x) * 8;
    int n = (int)(base & (NPIX - 1));
    const float* rs = rsum + (size_t)gb*NPIX;
    uint4 v = *(const uint4*)&Vt[base];
    const unsigned short* s = (const unsigned short*)&v;
    unsigned short pk[8];
    #pragma unroll
    for (int i = 0; i < 8; i++)
        pk[i] = f2bf(bf2f(s[i]) / (rs[n + i] + 1e-14f));
    *(uint4*)&Vp[base] = *(uint4*)pk;
}

// ---------------------------------------------------------------------------
// out[c][m] = sum_n V'[c][n] * St[m][n] + feat[c][m].
// Single-barrier merged-phase counted-vmcnt pipeline (LDS A+B, revert of
// R6's failed global-A port-split):
//   BM=128(c) x BN=256(m) x BK=64, 512 thr (8 waves 2x4, 64x64/wave),
//   3 LDS buffers (144 KiB), depth-2 prefetch, ONE s_barrier per K-step.
//   Per step: 16 ds_reads + 6 stages (tile s+2) + 32-MFMA setprio cluster +
//   vmcnt(6) + barrier. Waves may slip within a step -> one wave's ds_reads
//   overlap another's MFMAs (no intra-step lockstep). WAR-safe: stage into
//   buffer (s+2)%3 follows the step-(s-1) end barrier, which its last
//   readers' ds_reads precede; the end barrier also blocks fast waves from
//   staging over slow waves' current reads.
// grid (16, 4, nb); block 512. 1 block/CU (256 blocks at nb=4).
// ---------------------------------------------------------------------------
#define PVBUF 24576          // shorts per buffer: A 128*64 + B 256*64
#define PVNT  (NPIX/BK)      // 64 K-tiles

__global__ __launch_bounds__(512)
void pv_mfma(const unsigned short* __restrict__ Vp_,
             const unsigned short* __restrict__ St_,
             const float* __restrict__ feat_, float* __restrict__ out_,
             int b0)
{
    __shared__ unsigned short SH3[3*PVBUF];   // 147456 B
    const int tid = threadIdx.x;
    const int wid = tid >> 6, lane = tid & 63, quad = lane >> 4, lo = lane & 15;
    const int wm = wid >> 2;          // 0..1 : c-dim (A operand)
    const int wn = wid & 3;           // 0..3 : m-dim (B operand)
    const int m0 = blockIdx.x * 256, c0 = blockIdx.y * 128;
    const int bz = blockIdx.z, gb = b0 + bz;

    const unsigned short* Vp = Vp_ + (size_t)gb*CH*NPIX;
    const unsigned short* St = St_ + (size_t)bz*NPIX*NPIX;
    const float* feat = feat_ + (size_t)gb*CH*NPIX;
    float* out = out_ + (size_t)gb*CH*NPIX;

    floatx4 acc[4][4] = {};   // [i: c frag][j: m frag]

    // ---- prologue: stage K-tile 0 -> buf0, K-tile 1 -> buf1 (12 loads/wave)
    {
        unsigned short* A0 = SH3;            unsigned short* B0 = SH3 + 128*64;
        unsigned short* A1 = SH3 + PVBUF;    unsigned short* B1 = A1  + 128*64;
        STG64(A0, Vp, c0, NPIX, 0, 0);  STG64(A0, Vp, c0, NPIX, 0, 1);
        STG64(B0, St, m0, NPIX, 0, 0);  STG64(B0, St, m0, NPIX, 0, 1);
        STG64(B0, St, m0, NPIX, 0, 2);  STG64(B0, St, m0, NPIX, 0, 3);
        STG64(A1, Vp, c0, NPIX, BK, 0); STG64(A1, Vp, c0, NPIX, BK, 1);
        STG64(B1, St, m0, NPIX, BK, 0); STG64(B1, St, m0, NPIX, BK, 1);
        STG64(B1, St, m0, NPIX, BK, 2); STG64(B1, St, m0, NPIX, BK, 3);
    }
    asm volatile("s_waitcnt vmcnt(6)" ::: "memory");   // K-tile 0 landed
    __builtin_amdgcn_s_barrier();

    int pc = 0, pn = 2;     // compute buf = s%3, stage buf = (s+2)%3
    for (int s = 0; s < PVNT; ++s) {
        unsigned short* Ac = SH3 + pc*PVBUF;
        unsigned short* Bc = Ac + 128*64;
        unsigned short* An = SH3 + pn*PVBUF;
        unsigned short* Bn = An + 128*64;
        const int k2 = (s + 2) * BK;
        const bool stg = (s < PVNT - 2);

        // merged phase: read all A + B frags for tile s; stage tile s+2
        short8 a0[2][4], b0[2][4];
        #pragma unroll
        for (int ks = 0; ks < 2; ks++) {
            #pragma unroll
            for (int i = 0; i < 4; i++)
                a0[ks][i] = FRAG(Ac, wm*64 + i*16 + lo, ks);
            #pragma unroll
            for (int j = 0; j < 4; j++)
                b0[ks][j] = FRAG(Bc, wn*64 + j*16 + lo, ks);
        }
        if (stg) {
            STG64(An, Vp, c0, NPIX, k2, 0);
            STG64(An, Vp, c0, NPIX, k2, 1);
            STG64(Bn, St, m0, NPIX, k2, 0);
            STG64(Bn, St, m0, NPIX, k2, 1);
            STG64(Bn, St, m0, NPIX, k2, 2);
            STG64(Bn, St, m0, NPIX, k2, 3);
        }
        __builtin_amdgcn_s_setprio(1);
        #pragma unroll
        for (int ks = 0; ks < 2; ks++)
            #pragma unroll
            for (int i = 0; i < 4; i++)
                #pragma unroll
                for (int j = 0; j < 4; j++)
                    acc[i][j] = __builtin_amdgcn_mfma_f32_16x16x32_bf16(
                        a0[ks][i], b0[ks][j], acc[i][j], 0, 0, 0);
        __builtin_amdgcn_s_setprio(0);

        // counted wait: tile s+1 complete; tile s+2 (6 loads) stays in flight
        if (stg)                asm volatile("s_waitcnt vmcnt(6)" ::: "memory");
        else if (s == PVNT - 2) asm volatile("s_waitcnt vmcnt(0)" ::: "memory");
        __builtin_amdgcn_s_barrier();

        pc = (pc == 2) ? 0 : pc + 1;
        pn = (pn == 2) ? 0 : pn + 1;
    }

    // epilogue: direct store out = acc + feat (16-lane / 64B contiguous runs)
    #pragma unroll
    for (int i = 0; i < 4; i++) {
        int cr = c0 + wm*64 + i*16 + quad*4;
        #pragma unroll
        for (int r = 0; r < 4; r++) {
            size_t rowbase = (size_t)(cr + r)*NPIX;
            #pragma unroll
            for (int j = 0; j < 4; j++) {
                int m = m0 + wn*64 + j*16 + lo;
                out[rowbase + m] = acc[i][j][r] + feat[rowbase + m];
            }
        }
    }
}

// ---------------------------------------------------------------------------
extern "C" void kernel_launch(void* const* d_in, const int* in_sizes, int n_in,
                              void* d_out, int out_size, void* d_ws, size_t ws_size,
                              hipStream_t stream)
{
    const float* feat = (const float*)d_in[0];
    const float* qw   = (const float*)d_in[1];
    const float* qb   = (const float*)d_in[2];
    const float* kw   = (const float*)d_in[3];
    const float* kb   = (const float*)d_in[4];
    const float* vw   = (const float*)d_in[5];
    const float* vb   = (const float*)d_in[6];
    const float* cw   = (const float*)d_in[7];
    const float* cb   = (const float*)d_in[8];
    float* out = (float*)d_out;
    char* ws = (char*)d_ws;
    char* ws0 = ws;

    unsigned short* Ft  = (unsigned short*)ws;  ws += (size_t)BATCH*NPIX*CH*2;   // 16.78 MB
    unsigned short* Wb  = (unsigned short*)ws;  ws += (size_t)1024*CH*2;         // 1.05 MB
    unsigned short* Qt  = (unsigned short*)ws;  ws += (size_t)BATCH*NPIX*ICH*2;  // 8.39 MB
    unsigned short* Kt  = (unsigned short*)ws;  ws += (size_t)BATCH*NPIX*ICH*2;  // 8.39 MB
    unsigned short* Vt  = (unsigned short*)ws;  ws += (size_t)BATCH*CH*NPIX*2;   // 16.78 MB
    unsigned short* Vp  = (unsigned short*)ws;  ws += (size_t)BATCH*CH*NPIX*2;   // 16.78 MB
    float*         asq  = (float*)ws;           ws += (size_t)BATCH*NPIX*4;
    float*         bsq  = (float*)ws;           ws += (size_t)BATCH*NPIX*4;
    float*         rsum = (float*)ws;           ws += (size_t)BATCH*NPIX*4;
    unsigned short* St  = (unsigned short*)ws;  // nb * 33.55 MB

    const size_t st1 = (size_t)NPIX*NPIX*2;
    const size_t fixed = (size_t)(ws - ws0);
    const int nb = (ws_size >= fixed + (size_t)BATCH*st1) ? BATCH : 1;

    hipMemsetAsync(rsum, 0, (size_t)BATCH*NPIX*sizeof(float), stream);

    prep_w<<<dim3(512), 256, 0, stream>>>(qw, kw, vw, Wb);
    prep_ft<<<dim3(NPIX/64, CH/64, BATCH), 256, 0, stream>>>(feat, Ft);

    conv_mfma<<<dim3(NPIX/128, 8, BATCH), 256, 0, stream>>>(
        Ft, Wb, qb, kb, vb, cw, cb, Qt, Kt, Vt);

    sqb_kernel<<<dim3(NPIX/256, BATCH), 256, 0, stream>>>(Qt, Kt, asq, bsq);

    for (int b0 = 0; b0 < BATCH; b0 += nb) {
        dots_mfma<<<dim3(NPIX/128, NPIX/128, nb), 512, 0, stream>>>(
            Kt, Qt, asq, bsq, St, rsum, b0);
        vscale_kernel<<<dim3(CH*NPIX/(256*8), nb), 256, 0, stream>>>(
            Vt, rsum, Vp, b0);
        pv_mfma<<<dim3(NPIX/256, CH/128, nb), 512, 0, stream>>>(
            Vp, St, feat, out, b0);
    }
}

// Round 8
// 271.591 us; speedup vs baseline: 1.4044x; 1.0845x over previous
//
#include <hip/hip_runtime.h>
#include <math.h>

#define BATCH 4
#define CH    512
#define ICH   256
#define NPIX  4096   // 64*64

typedef short short8 __attribute__((ext_vector_type(8)));
typedef float floatx4 __attribute__((ext_vector_type(4)));

#define BK   64
#define TS   136   // epilogue LDS tile stride (272B rows; <=2-way bank alias)

static __device__ __forceinline__ unsigned short f2bf(float x) {
    union { float f; unsigned u; } v; v.f = x;
    unsigned r = (v.u + 0x7FFF + ((v.u >> 16) & 1)) >> 16;   // RNE
    return (unsigned short)r;
}
static __device__ __forceinline__ float bf2f(unsigned short u) {
    union { unsigned u; float f; } v; v.u = ((unsigned)u) << 16; return v.f;
}
// pack two fp32 (even lane's, odd lane's) to bf16 pair, round-half-up
static __device__ __forceinline__ unsigned pack_bf(unsigned ue, unsigned uo) {
    return ((ue + 0x8000u) >> 16) | ((uo + 0x8000u) & 0xFFFF0000u);
}

// async global->LDS, 16B per lane. dst must be wave-uniform; HW adds lane*16.
static __device__ __forceinline__ void gld16(const unsigned short* g, unsigned short* l) {
    __builtin_amdgcn_global_load_lds(
        (const __attribute__((address_space(1))) unsigned int*)g,
        (__attribute__((address_space(3))) unsigned int*)l,
        16, 0, 0);
}

// 512-thread staging (8 waves, 64 rows per issue) — used by all MFMA kernels.
#define STG64(L, M, row0, RS, k0, u)                                          \
    {                                                                         \
        int r_  = (u)*64 + wid*8 + (lane >> 3);                               \
        int c_  = (lane & 7) ^ ((lane >> 3) & 7);                             \
        gld16(&(M)[(size_t)((row0) + r_)*(RS) + (k0) + c_*8],                 \
              &(L)[((u)*64 + wid*8)*64]);                                     \
    }

#define FRAG(L, row, ks) \
    (*(const short8*)&(L)[(row)*64 + (((((ks)<<2) + quad) ^ (lo & 7)) << 3)])

// ---------------------------------------------------------------------------
// prep_w: qw/kw/vw fp32 -> Wb[1024][512] bf16 (rows: 0-255 Q, 256-511 K, 512-1023 V)
// ---------------------------------------------------------------------------
__global__ __launch_bounds__(256)
void prep_w(const float* __restrict__ qw, const float* __restrict__ kw,
            const float* __restrict__ vw, unsigned short* __restrict__ Wb)
{
    int i = (blockIdx.x*256 + threadIdx.x) * 4;
    const float* src;
    int off;
    if (i < 256*512)            { src = qw; off = i; }
    else if (i < 512*512)       { src = kw; off = i - 256*512; }
    else                        { src = vw; off = i - 512*512; }
    float4 f = *(const float4*)&src[off];
    unsigned short pk[4] = { f2bf(f.x), f2bf(f.y), f2bf(f.z), f2bf(f.w) };
    *(uint2*)&Wb[i] = *(uint2*)pk;
}

// ---------------------------------------------------------------------------
// prep_ft: feat [b][c][n] fp32 -> Ft [b][n][c] bf16. grid (64, 8, B).
// ---------------------------------------------------------------------------
__global__ __launch_bounds__(256)
void prep_ft(const float* __restrict__ feat, unsigned short* __restrict__ Ft)
{
    __shared__ unsigned short S[64][65];
    const int t = threadIdx.x;
    const int n0 = blockIdx.x * 64, c0 = blockIdx.y * 64, b = blockIdx.z;

    #pragma unroll
    for (int rep = 0; rep < 4; rep++) {
        int cl = rep*16 + (t >> 4), col4 = (t & 15) * 4;
        float4 f = *(const float4*)&feat[((size_t)b*CH + c0 + cl)*NPIX + n0 + col4];
        S[cl][col4 + 0] = f2bf(f.x);
        S[cl][col4 + 1] = f2bf(f.y);
        S[cl][col4 + 2] = f2bf(f.z);
        S[cl][col4 + 3] = f2bf(f.w);
    }
    __syncthreads();
    #pragma unroll
    for (int rep = 0; rep < 4; rep++) {
        int nn = rep*16 + (t >> 4), cq = t & 15;
        unsigned short h4[4];
        #pragma unroll
        for (int j = 0; j < 4; j++) h4[j] = S[cq*4 + j][nn];
        *(uint2*)&Ft[((size_t)b*NPIX + n0 + nn)*CH + c0 + cq*4] = *(uint2*)h4;
    }
}

// ---------------------------------------------------------------------------
// conv_mfma: fused QKV conv as bf16 MFMA GEMM, K=512.
// High-TLP form (R5 dots transform): 512 threads / 8 waves on the same
// 128x128 tile (wave-tile 64x32, acc[4][2]). Same 34.8KB LDS -> 4 blocks/CU,
// now 32 waves/CU; serial staging latency hidden by TLP.
// grid (32, 8, B); block 512.
// ---------------------------------------------------------------------------
__global__ __launch_bounds__(512)
void conv_mfma(const unsigned short* __restrict__ Ft,
               const unsigned short* __restrict__ Wb,
               const float* __restrict__ qb, const float* __restrict__ kb,
               const float* __restrict__ vb,
               const float* __restrict__ cw, const float* __restrict__ cb,
               unsigned short* __restrict__ Qt, unsigned short* __restrict__ Kt,
               unsigned short* __restrict__ Vt)
{
    __shared__ unsigned short SH[128*TS];   // 34816B; staging uses first 32KB
    unsigned short* L0 = SH;                // Ft tile (rows n), 128*64
    unsigned short* L2 = SH + 128*64;       // W tile (rows o), 128*64

    const int tid = threadIdx.x;
    const int wid = tid >> 6, lane = tid & 63, quad = lane >> 4, lo = lane & 15;
    const int n0 = blockIdx.x * 128;
    const int yb = blockIdx.y;
    const int bz = blockIdx.z;
    const int o_base = yb * 128;
    const int wm = wid >> 2;          // 0..1 : row strip (64)
    const int wn = wid & 3;           // 0..3 : col strip (32)
    const int is_v = (yb >= 4);
    const size_t fb = (size_t)bz*NPIX;

    floatx4 acc[4][2] = {};

    for (int k0 = 0; k0 < CH; k0 += BK) {
        STG64(L0, Ft, fb + n0, CH, k0, 0);
        STG64(L0, Ft, fb + n0, CH, k0, 1);
        STG64(L2, Wb, o_base,  CH, k0, 0);
        STG64(L2, Wb, o_base,  CH, k0, 1);
        __syncthreads();
        if (!is_v) {
            #pragma unroll
            for (int ks = 0; ks < 2; ks++) {
                short8 af[4], bw[2];
                #pragma unroll
                for (int i = 0; i < 4; i++) af[i] = FRAG(L0, wm*64 + i*16 + lo, ks);
                #pragma unroll
                for (int j = 0; j < 2; j++) bw[j] = FRAG(L2, wn*32 + j*16 + lo, ks);
                #pragma unroll
                for (int i = 0; i < 4; i++)
                    #pragma unroll
                    for (int j = 0; j < 2; j++)
                        acc[i][j] = __builtin_amdgcn_mfma_f32_16x16x32_bf16(af[i], bw[j], acc[i][j], 0, 0, 0);
            }
        } else {
            #pragma unroll
            for (int ks = 0; ks < 2; ks++) {
                short8 aw[4], bf[2];
                #pragma unroll
                for (int i = 0; i < 4; i++) aw[i] = FRAG(L2, wm*64 + i*16 + lo, ks);
                #pragma unroll
                for (int j = 0; j < 2; j++) bf[j] = FRAG(L0, wn*32 + j*16 + lo, ks);
                #pragma unroll
                for (int i = 0; i < 4; i++)
                    #pragma unroll
                    for (int j = 0; j < 2; j++)
                        acc[i][j] = __builtin_amdgcn_mfma_f32_16x16x32_bf16(aw[i], bf[j], acc[i][j], 0, 0, 0);
            }
        }
        __syncthreads();
    }

    // epilogue phase 1: values -> LDS tile [row 128][col 128], pair-packed dwords.
    const float step = 2.0f / 63.0f;
    if (!is_v) {
        const float* bp = (yb < 2) ? qb : kb;
        const int icg0 = (yb & 1) * 128;
        #pragma unroll
        for (int ib = 0; ib < 2; ib++) {
            int colL = wn*32 + ib*16 + lo;
            int ic = icg0 + colL;
            float bias = bp[ic];
            float cw0 = cw[ic*2+0], cw1 = cw[ic*2+1], cbv = cb[ic];
            #pragma unroll
            for (int ia = 0; ia < 4; ia++) {
                int rowL = wm*64 + ia*16 + quad*4;
                #pragma unroll
                for (int r = 0; r < 4; r++) {
                    int n = n0 + rowL + r;
                    float cx = -1.f + (n & 63)*step;
                    float cy = -1.f + (n >> 6)*step;
                    float v = fmaxf(acc[ia][ib][r] + bias, 0.f)
                            + fmaxf(cw0*cx + cw1*cy + cbv, 0.f);
                    unsigned u = __float_as_uint(v);
                    unsigned p = __shfl_xor(u, 1, 64);
                    if ((lo & 1) == 0)
                        *(unsigned*)&SH[(rowL + r)*TS + colL] = pack_bf(u, p);
                }
            }
        }
    } else {
        const int c_blk0 = (yb - 4) * 128;
        #pragma unroll
        for (int ia = 0; ia < 4; ia++) {
            int rowL = wm*64 + ia*16 + quad*4;
            #pragma unroll
            for (int r = 0; r < 4; r++) {
                float bias = vb[c_blk0 + rowL + r];
                #pragma unroll
                for (int ib = 0; ib < 2; ib++) {
                    int colL = wn*32 + ib*16 + lo;
                    float v = fmaxf(acc[ia][ib][r] + bias, 0.f);
                    unsigned u = __float_as_uint(v);
                    unsigned p = __shfl_xor(u, 1, 64);
                    if ((lo & 1) == 0)
                        *(unsigned*)&SH[(rowL + r)*TS + colL] = pack_bf(u, p);
                }
            }
        }
    }
    __syncthreads();

    // epilogue phase 2: coalesced copy to global (256B per row segment)
    unsigned short* dstp;
    int row0, rs, col0;
    if (!is_v) { dstp = ((yb < 2) ? Qt : Kt) + (size_t)bz*NPIX*ICH;
                 row0 = n0; rs = ICH; col0 = (yb & 1) * 128; }
    else       { dstp = Vt + (size_t)bz*CH*NPIX;
                 row0 = (yb - 4) * 128; rs = NPIX; col0 = n0; }
    #pragma unroll
    for (int it = 0; it < 4; it++) {
        int f = it*512 + tid;
        int row = f >> 4, col = (f & 15) * 8;
        uint4 v = *(const uint4*)&SH[row*TS + col];
        *(uint4*)&dstp[(size_t)(row0 + row)*rs + col0 + col] = v;
    }
}

// ---------------------------------------------------------------------------
// asq[n] = |q_n|^2, bsq[n] = |k_n|^2 from bf16 Qt/Kt [n][ic]. grid (16, B).
// ---------------------------------------------------------------------------
__global__ __launch_bounds__(256)
void sqb_kernel(const unsigned short* __restrict__ Qt,
                const unsigned short* __restrict__ Kt,
                float* __restrict__ asq, float* __restrict__ bsq)
{
    int n = blockIdx.x*256 + threadIdx.x;
    int b = blockIdx.y;
    const unsigned short* q = Qt + ((size_t)b*NPIX + n)*ICH;
    const unsigned short* k = Kt + ((size_t)b*NPIX + n)*ICH;
    float qs = 0.f, ks = 0.f;
    #pragma unroll 4
    for (int i = 0; i < ICH/8; i++) {
        uint4 v = *(const uint4*)&q[i*8];
        const unsigned short* s = (const unsigned short*)&v;
        #pragma unroll
        for (int j = 0; j < 8; j++) { float a = bf2f(s[j]); qs += a*a; }
        uint4 w = *(const uint4*)&k[i*8];
        const unsigned short* t = (const unsigned short*)&w;
        #pragma unroll
        for (int j = 0; j < 8; j++) { float a = bf2f(t[j]); ks += a*a; }
    }
    asq[b*NPIX + n] = qs;
    bsq[b*NPIX + n] = ks;
}

// ---------------------------------------------------------------------------
// St[bz][m][n] = exp(-(asq[n]+bsq[m]-2*k_m.q_n)) bf16 + col sums -> rsum[n].
// High-TLP: 128x128 tile, serial K-loop, 512 threads / 8 waves
// (wave-tile 64x32, acc[4][2]). 32 waves/CU. Epilogue uses exp2 with
// hoisted log2e-scaled bases (saves one v_mul per value).
// grid (32, 32, nb); block 512. LDS 34.8KB.
// ---------------------------------------------------------------------------
__global__ __launch_bounds__(512)
void dots_mfma(const unsigned short* __restrict__ Kt_,
               const unsigned short* __restrict__ Qt_,
               const float* __restrict__ asq_, const float* __restrict__ bsq_,
               unsigned short* __restrict__ St_, float* __restrict__ rsum_,
               int b0)
{
    __shared__ unsigned short SH[128*TS];   // 34816B; staging uses first 32KB
    unsigned short* Al = SH;                // Kt tile (rows m), 128*64
    unsigned short* Bl = SH + 8192;         // Qt tile (rows n), 128*64

    const int tid = threadIdx.x;
    const int wid = tid >> 6, lane = tid & 63, quad = lane >> 4, lo = lane & 15;
    const int wm = wid >> 2;          // 0..1 : m-dim (64 rows each)
    const int wn = wid & 3;           // 0..3 : n-dim (32 cols each)
    const int m0 = blockIdx.x * 128, n0 = blockIdx.y * 128;
    const int bz = blockIdx.z, gb = b0 + bz;

    const unsigned short* Kt = Kt_ + (size_t)gb*NPIX*ICH;
    const unsigned short* Qt = Qt_ + (size_t)gb*NPIX*ICH;
    const float* asq = asq_ + (size_t)gb*NPIX;
    const float* bsq = bsq_ + (size_t)gb*NPIX;
    unsigned short* St = St_ + (size_t)bz*NPIX*NPIX;
    float* rsum = rsum_ + (size_t)gb*NPIX;

    floatx4 acc[4][2] = {};   // [i: m frag][j: n frag]

    for (int k0 = 0; k0 < ICH; k0 += BK) {
        STG64(Al, Kt, m0, ICH, k0, 0);
        STG64(Al, Kt, m0, ICH, k0, 1);
        STG64(Bl, Qt, n0, ICH, k0, 0);
        STG64(Bl, Qt, n0, ICH, k0, 1);
        __syncthreads();
        #pragma unroll
        for (int ks = 0; ks < 2; ks++) {
            short8 a[4], bfr[2];
            #pragma unroll
            for (int i = 0; i < 4; i++) a[i]  = FRAG(Al, wm*64 + i*16 + lo, ks);
            #pragma unroll
            for (int j = 0; j < 2; j++) bfr[j] = FRAG(Bl, wn*32 + j*16 + lo, ks);
            #pragma unroll
            for (int i = 0; i < 4; i++)
                #pragma unroll
                for (int j = 0; j < 2; j++)
                    acc[i][j] = __builtin_amdgcn_mfma_f32_16x16x32_bf16(
                        a[i], bfr[j], acc[i][j], 0, 0, 0);
        }
        __syncthreads();
    }

    // epilogue phase 1: exp2-based exp(-D) -> LDS tile (pair-pack), colsums
    const float L2E  = 1.44269504f;      // log2(e)
    const float L2E2 = 2.88539008f;      // 2*log2(e)
    float bL[4][4];
    #pragma unroll
    for (int i = 0; i < 4; i++) {
        int mb = wm*64 + i*16 + quad*4;
        #pragma unroll
        for (int r = 0; r < 4; r++) bL[i][r] = bsq[m0 + mb + r] * L2E;
    }
    #pragma unroll
    for (int j = 0; j < 2; j++) {
        int nl = wn*32 + j*16 + lo;
        float aqL = asq[n0 + nl] * L2E;
        float colsum = 0.f;
        #pragma unroll
        for (int i = 0; i < 4; i++) {
            int mb = wm*64 + i*16 + quad*4;
            #pragma unroll
            for (int r = 0; r < 4; r++) {
                // exp(-(aq+bsq-2acc)) = 2^(2*L2E*acc - aqL - bL)
                float sv = exp2f(fmaf(acc[i][j][r], L2E2, -(aqL + bL[i][r])));
                colsum += sv;
                unsigned u = __float_as_uint(sv);
                unsigned p = __shfl_xor(u, 1, 64);
                if ((lo & 1) == 0)
                    *(unsigned*)&SH[(mb + r)*TS + nl] = pack_bf(u, p);
            }
        }
        colsum += __shfl_xor(colsum, 16, 64);
        colsum += __shfl_xor(colsum, 32, 64);
        if (quad == 0) atomicAdd(&rsum[n0 + nl], colsum);
    }
    __syncthreads();

    // epilogue phase 2: coalesced store, 256B contiguous per row
    #pragma unroll
    for (int it = 0; it < 4; it++) {
        int f = it*512 + tid;
        int row = f >> 4, col = (f & 15) * 8;
        uint4 v = *(const uint4*)&SH[row*TS + col];
        *(uint4*)&St[(size_t)(m0 + row)*NPIX + n0 + col] = v;
    }
}

// ---------------------------------------------------------------------------
// Vp[c][n] = bf16( Vt[c][n] / (rsum[n] + 1e-14) ). grid (1024, nb).
// v_rcp_f32 instead of full-precision divide (error << bf16 rounding).
// ---------------------------------------------------------------------------
__global__ __launch_bounds__(256)
void vscale_kernel(const unsigned short* __restrict__ Vt,
                   const float* __restrict__ rsum,
                   unsigned short* __restrict__ Vp, int b0)
{
    int gb = b0 + blockIdx.y;
    size_t base = (size_t)gb*CH*NPIX + ((size_t)blockIdx.x*256 + threadIdx.x) * 8;
    int n = (int)(base & (NPIX - 1));
    const float* rs = rsum + (size_t)gb*NPIX;
    uint4 v = *(const uint4*)&Vt[base];
    const unsigned short* s = (const unsigned short*)&v;
    unsigned short pk[8];
    #pragma unroll
    for (int i = 0; i < 8; i++)
        pk[i] = f2bf(bf2f(s[i]) * __builtin_amdgcn_rcpf(rs[n + i] + 1e-14f));
    *(uint4*)&Vp[base] = *(uint4*)pk;
}

// ---------------------------------------------------------------------------
// out[c][m] = sum_n V'[c][n] * St[m][n] + feat[c][m].
// Single-barrier merged-phase counted-vmcnt pipeline:
//   BM=128(c) x BN=256(m) x BK=64, 512 thr (8 waves 2x4, 64x64/wave),
//   3 LDS buffers (144 KiB), depth-2 prefetch, ONE s_barrier per K-step.
// grid (16, 4, nb); block 512. 1 block/CU (256 blocks at nb=4).
// ---------------------------------------------------------------------------
#define PVBUF 24576          // shorts per buffer: A 128*64 + B 256*64
#define PVNT  (NPIX/BK)      // 64 K-tiles

__global__ __launch_bounds__(512)
void pv_mfma(const unsigned short* __restrict__ Vp_,
             const unsigned short* __restrict__ St_,
             const float* __restrict__ feat_, float* __restrict__ out_,
             int b0)
{
    __shared__ unsigned short SH3[3*PVBUF];   // 147456 B
    const int tid = threadIdx.x;
    const int wid = tid >> 6, lane = tid & 63, quad = lane >> 4, lo = lane & 15;
    const int wm = wid >> 2;          // 0..1 : c-dim (A operand)
    const int wn = wid & 3;           // 0..3 : m-dim (B operand)
    const int m0 = blockIdx.x * 256, c0 = blockIdx.y * 128;
    const int bz = blockIdx.z, gb = b0 + bz;

    const unsigned short* Vp = Vp_ + (size_t)gb*CH*NPIX;
    const unsigned short* St = St_ + (size_t)bz*NPIX*NPIX;
    const float* feat = feat_ + (size_t)gb*CH*NPIX;
    float* out = out_ + (size_t)gb*CH*NPIX;

    floatx4 acc[4][4] = {};   // [i: c frag][j: m frag]

    // ---- prologue: stage K-tile 0 -> buf0, K-tile 1 -> buf1 (12 loads/wave)
    {
        unsigned short* A0 = SH3;            unsigned short* B0 = SH3 + 128*64;
        unsigned short* A1 = SH3 + PVBUF;    unsigned short* B1 = A1  + 128*64;
        STG64(A0, Vp, c0, NPIX, 0, 0);  STG64(A0, Vp, c0, NPIX, 0, 1);
        STG64(B0, St, m0, NPIX, 0, 0);  STG64(B0, St, m0, NPIX, 0, 1);
        STG64(B0, St, m0, NPIX, 0, 2);  STG64(B0, St, m0, NPIX, 0, 3);
        STG64(A1, Vp, c0, NPIX, BK, 0); STG64(A1, Vp, c0, NPIX, BK, 1);
        STG64(B1, St, m0, NPIX, BK, 0); STG64(B1, St, m0, NPIX, BK, 1);
        STG64(B1, St, m0, NPIX, BK, 2); STG64(B1, St, m0, NPIX, BK, 3);
    }
    asm volatile("s_waitcnt vmcnt(6)" ::: "memory");   // K-tile 0 landed
    __builtin_amdgcn_s_barrier();

    int pc = 0, pn = 2;     // compute buf = s%3, stage buf = (s+2)%3
    for (int s = 0; s < PVNT; ++s) {
        unsigned short* Ac = SH3 + pc*PVBUF;
        unsigned short* Bc = Ac + 128*64;
        unsigned short* An = SH3 + pn*PVBUF;
        unsigned short* Bn = An + 128*64;
        const int k2 = (s + 2) * BK;
        const bool stg = (s < PVNT - 2);

        // merged phase: read all A + B frags for tile s; stage tile s+2
        short8 a0[2][4], b0[2][4];
        #pragma unroll
        for (int ks = 0; ks < 2; ks++) {
            #pragma unroll
            for (int i = 0; i < 4; i++)
                a0[ks][i] = FRAG(Ac, wm*64 + i*16 + lo, ks);
            #pragma unroll
            for (int j = 0; j < 4; j++)
                b0[ks][j] = FRAG(Bc, wn*64 + j*16 + lo, ks);
        }
        if (stg) {
            STG64(An, Vp, c0, NPIX, k2, 0);
            STG64(An, Vp, c0, NPIX, k2, 1);
            STG64(Bn, St, m0, NPIX, k2, 0);
            STG64(Bn, St, m0, NPIX, k2, 1);
            STG64(Bn, St, m0, NPIX, k2, 2);
            STG64(Bn, St, m0, NPIX, k2, 3);
        }
        __builtin_amdgcn_s_setprio(1);
        #pragma unroll
        for (int ks = 0; ks < 2; ks++)
            #pragma unroll
            for (int i = 0; i < 4; i++)
                #pragma unroll
                for (int j = 0; j < 4; j++)
                    acc[i][j] = __builtin_amdgcn_mfma_f32_16x16x32_bf16(
                        a0[ks][i], b0[ks][j], acc[i][j], 0, 0, 0);
        __builtin_amdgcn_s_setprio(0);

        // counted wait: tile s+1 complete; tile s+2 (6 loads) stays in flight
        if (stg)                asm volatile("s_waitcnt vmcnt(6)" ::: "memory");
        else if (s == PVNT - 2) asm volatile("s_waitcnt vmcnt(0)" ::: "memory");
        __builtin_amdgcn_s_barrier();

        pc = (pc == 2) ? 0 : pc + 1;
        pn = (pn == 2) ? 0 : pn + 1;
    }

    // epilogue: direct store out = acc + feat (16-lane / 64B contiguous runs)
    #pragma unroll
    for (int i = 0; i < 4; i++) {
        int cr = c0 + wm*64 + i*16 + quad*4;
        #pragma unroll
        for (int r = 0; r < 4; r++) {
            size_t rowbase = (size_t)(cr + r)*NPIX;
            #pragma unroll
            for (int j = 0; j < 4; j++) {
                int m = m0 + wn*64 + j*16 + lo;
                out[rowbase + m] = acc[i][j][r] + feat[rowbase + m];
            }
        }
    }
}

// ---------------------------------------------------------------------------
extern "C" void kernel_launch(void* const* d_in, const int* in_sizes, int n_in,
                              void* d_out, int out_size, void* d_ws, size_t ws_size,
                              hipStream_t stream)
{
    const float* feat = (const float*)d_in[0];
    const float* qw   = (const float*)d_in[1];
    const float* qb   = (const float*)d_in[2];
    const float* kw   = (const float*)d_in[3];
    const float* kb   = (const float*)d_in[4];
    const float* vw   = (const float*)d_in[5];
    const float* vb   = (const float*)d_in[6];
    const float* cw   = (const float*)d_in[7];
    const float* cb   = (const float*)d_in[8];
    float* out = (float*)d_out;
    char* ws = (char*)d_ws;
    char* ws0 = ws;

    unsigned short* Ft  = (unsigned short*)ws;  ws += (size_t)BATCH*NPIX*CH*2;   // 16.78 MB
    unsigned short* Wb  = (unsigned short*)ws;  ws += (size_t)1024*CH*2;         // 1.05 MB
    unsigned short* Qt  = (unsigned short*)ws;  ws += (size_t)BATCH*NPIX*ICH*2;  // 8.39 MB
    unsigned short* Kt  = (unsigned short*)ws;  ws += (size_t)BATCH*NPIX*ICH*2;  // 8.39 MB
    unsigned short* Vt  = (unsigned short*)ws;  ws += (size_t)BATCH*CH*NPIX*2;   // 16.78 MB
    unsigned short* Vp  = (unsigned short*)ws;  ws += (size_t)BATCH*CH*NPIX*2;   // 16.78 MB
    float*         asq  = (float*)ws;           ws += (size_t)BATCH*NPIX*4;
    float*         bsq  = (float*)ws;           ws += (size_t)BATCH*NPIX*4;
    float*         rsum = (float*)ws;           ws += (size_t)BATCH*NPIX*4;
    unsigned short* St  = (unsigned short*)ws;  // nb * 33.55 MB

    const size_t st1 = (size_t)NPIX*NPIX*2;
    const size_t fixed = (size_t)(ws - ws0);
    const int nb = (ws_size >= fixed + (size_t)BATCH*st1) ? BATCH : 1;

    hipMemsetAsync(rsum, 0, (size_t)BATCH*NPIX*sizeof(float), stream);

    prep_w<<<dim3(512), 256, 0, stream>>>(qw, kw, vw, Wb);
    prep_ft<<<dim3(NPIX/64, CH/64, BATCH), 256, 0, stream>>>(feat, Ft);

    conv_mfma<<<dim3(NPIX/128, 8, BATCH), 512, 0, stream>>>(
        Ft, Wb, qb, kb, vb, cw, cb, Qt, Kt, Vt);

    sqb_kernel<<<dim3(NPIX/256, BATCH), 256, 0, stream>>>(Qt, Kt, asq, bsq);

    for (int b0 = 0; b0 < BATCH; b0 += nb) {
        dots_mfma<<<dim3(NPIX/128, NPIX/128, nb), 512, 0, stream>>>(
            Kt, Qt, asq, bsq, St, rsum, b0);
        vscale_kernel<<<dim3(CH*NPIX/(256*8), nb), 256, 0, stream>>>(
            Vt, rsum, Vp, b0);
        pv_mfma<<<dim3(NPIX/256, CH/128, nb), 512, 0, stream>>>(
            Vp, St, feat, out, b0);
    }
}